// Round 2
// baseline (223.034 us; speedup 1.0000x reference)
//
#include <hip/hip_runtime.h>
#include <hip/hip_bf16.h>
#include <math.h>

#define S_LEN 2048
#define N1 16
#define D 128
#define H 8
#define DI 128
#define K_SEL 512
#define SCALE_F 0.08838834764831845f  /* 1/sqrt(128) */
#define EPS_F 1e-9f

__global__ __launch_bounds__(256)
void sli_kl_kernel(const float* __restrict__ query,
                   const float* __restrict__ key,
                   const float* __restrict__ qidx,
                   const float* __restrict__ kidx,
                   const float* __restrict__ weights,
                   const int* __restrict__ sidx,
                   const float* __restrict__ smax,
                   const float* __restrict__ ssum,
                   float* __restrict__ out) {
  const int t = blockIdx.x;
  const int tid = threadIdx.x;
  const int lane = tid & 63;
  const int wid = tid >> 6;

  __shared__ float a_lds[K_SEL];
  __shared__ float e_lds[K_SEL];
  __shared__ float red[5][4];

  // Block-uniform row pointers (scalar-load friendly).
  const float4* __restrict__ qrow = (const float4*)(query + (size_t)t * N1 * D);
  const float4* __restrict__ qirow = (const float4*)(qidx + (size_t)t * H * DI);

  // Row-uniform constants hoisted out of the k loop:
  // exp(s - m)/l == exp(s) * (exp(-m)/l)  -> one mul per (n,k), no division.
  float cn[N1];
#pragma unroll
  for (int n = 0; n < N1; ++n) {
    const float m = smax[n * S_LEN + t];
    const float l = ssum[n * S_LEN + t];
    cn[n] = __expf(-m) / l;
  }
  float wgt[H];
#pragma unroll
  for (int h = 0; h < H; ++h) wgt[h] = weights[t * H + h];

  // Each thread owns two selected columns, processed jointly so every
  // (uniform) q load feeds 8 FMAs.
  const int k0 = tid;
  const int k1 = tid + 256;
  const int s0 = sidx[t * K_SEL + k0];
  const int s1 = sidx[t * K_SEL + k1];
  const float4* __restrict__ kp0 = (const float4*)(key + (size_t)s0 * D);
  const float4* __restrict__ kp1 = (const float4*)(key + (size_t)s1 * D);
  const float4* __restrict__ kip0 = (const float4*)(kidx + (size_t)s0 * DI);
  const float4* __restrict__ kip1 = (const float4*)(kidx + (size_t)s1 * DI);

  float accp0[N1], accp1[N1], acci0[H], acci1[H];
#pragma unroll
  for (int n = 0; n < N1; ++n) { accp0[n] = 0.f; accp1[n] = 0.f; }
#pragma unroll
  for (int h = 0; h < H; ++h) { acci0[h] = 0.f; acci1[h] = 0.f; }

#pragma unroll 2
  for (int c = 0; c < D / 8; ++c) {
    // 8 gathers in flight per trip (key/kidx stay L2-resident).
    float4 kv0[2], kv1[2], kiv0[2], kiv1[2];
#pragma unroll
    for (int j = 0; j < 2; ++j) {
      kv0[j] = kp0[2 * c + j];
      kv1[j] = kp1[2 * c + j];
      kiv0[j] = kip0[2 * c + j];
      kiv1[j] = kip1[2 * c + j];
    }
#pragma unroll
    for (int j = 0; j < 2; ++j) {
      const int d4 = 2 * c + j;
#pragma unroll
      for (int n = 0; n < N1; ++n) {
        const float4 qv = qrow[n * (D / 4) + d4];
        float a0 = accp0[n], a1 = accp1[n];
        a0 = fmaf(qv.x, kv0[j].x, a0); a1 = fmaf(qv.x, kv1[j].x, a1);
        a0 = fmaf(qv.y, kv0[j].y, a0); a1 = fmaf(qv.y, kv1[j].y, a1);
        a0 = fmaf(qv.z, kv0[j].z, a0); a1 = fmaf(qv.z, kv1[j].z, a1);
        a0 = fmaf(qv.w, kv0[j].w, a0); a1 = fmaf(qv.w, kv1[j].w, a1);
        accp0[n] = a0; accp1[n] = a1;
      }
#pragma unroll
      for (int h = 0; h < H; ++h) {
        const float4 qv = qirow[h * (DI / 4) + d4];
        float a0 = acci0[h], a1 = acci1[h];
        a0 = fmaf(qv.x, kiv0[j].x, a0); a1 = fmaf(qv.x, kiv1[j].x, a1);
        a0 = fmaf(qv.y, kiv0[j].y, a0); a1 = fmaf(qv.y, kiv1[j].y, a1);
        a0 = fmaf(qv.z, kiv0[j].z, a0); a1 = fmaf(qv.z, kiv1[j].z, a1);
        acci0[h] = fmaf(qv.w, kiv0[j].w, a0);
        acci1[h] = fmaf(qv.w, kiv1[j].w, a1);
      }
    }
  }

  float pa0 = 0.f, pa1 = 0.f;
#pragma unroll
  for (int n = 0; n < N1; ++n) {
    pa0 = fmaf(__expf(accp0[n] * SCALE_F), cn[n], pa0);
    pa1 = fmaf(__expf(accp1[n] * SCALE_F), cn[n], pa1);
  }
  float ia0 = 0.f, ia1 = 0.f;
#pragma unroll
  for (int h = 0; h < H; ++h) {
    ia0 = fmaf(wgt[h], fmaxf(acci0[h], 0.f), ia0);
    ia1 = fmaf(wgt[h], fmaxf(acci1[h], 0.f), ia1);
  }
  a_lds[k0] = pa0; a_lds[k1] = pa1;
  e_lds[k0] = ia0; e_lds[k1] = ia1;
  __syncthreads();

  // ---------- Row reductions ----------
  float la = 0.f, le = -INFINITY;
  for (int k = tid; k < K_SEL; k += 256) {
    la += a_lds[k];
    le = fmaxf(le, e_lds[k]);
  }
#pragma unroll
  for (int off = 32; off >= 1; off >>= 1) {
    la += __shfl_xor(la, off);
    le = fmaxf(le, __shfl_xor(le, off));
  }
  if (lane == 0) { red[0][wid] = la; red[1][wid] = le; }
  __syncthreads();
  const float S_a = red[0][0] + red[0][1] + red[0][2] + red[0][3];
  const float M = fmaxf(fmaxf(red[1][0], red[1][1]), fmaxf(red[1][2], red[1][3]));
  const float inv_sa = 1.f / (S_a + EPS_F);

  float z = 0.f, t1 = 0.f, t2 = 0.f;
  for (int k = tid; k < K_SEL; k += 256) {
    const float e = e_lds[k];
    const float pn = a_lds[k] * inv_sa;
    z += __expf(e - M);
    t1 += pn * __logf(pn + EPS_F);
    t2 += pn * e;
  }
#pragma unroll
  for (int off = 32; off >= 1; off >>= 1) {
    z += __shfl_xor(z, off);
    t1 += __shfl_xor(t1, off);
    t2 += __shfl_xor(t2, off);
  }
  if (lane == 0) { red[2][wid] = z; red[3][wid] = t1; red[4][wid] = t2; }
  __syncthreads();

  if (tid == 0) {
    const float Z = red[2][0] + red[2][1] + red[2][2] + red[2][3];
    const float T1 = red[3][0] + red[3][1] + red[3][2] + red[3][3];
    const float T2 = red[4][0] + red[4][1] + red[4][2] + red[4][3];
    const float total_pn = S_a * inv_sa;
    const float kl_row = T1 - T2 + (M + __logf(Z)) * total_pn;
    atomicAdd(out, kl_row * (1.0f / (float)S_LEN));
  }
}

extern "C" void kernel_launch(void* const* d_in, const int* in_sizes, int n_in,
                              void* d_out, int out_size, void* d_ws, size_t ws_size,
                              hipStream_t stream) {
  const float* query = (const float*)d_in[0];
  const float* key = (const float*)d_in[1];
  const float* qidx = (const float*)d_in[2];
  const float* kidx = (const float*)d_in[3];
  const float* weights = (const float*)d_in[4];
  const int* sidx = (const int*)d_in[5];
  const float* smax = (const float*)d_in[6];
  const float* ssum = (const float*)d_in[7];
  float* out = (float*)d_out;

  hipMemsetAsync(out, 0, sizeof(float), stream);
  sli_kl_kernel<<<dim3(S_LEN), dim3(256), 0, stream>>>(
      query, key, qidx, kidx, weights, sidx, smax, ssum, out);
}

// Round 3
// 74.238 us; speedup vs baseline: 3.0043x; 3.0043x over previous
//
#include <hip/hip_runtime.h>
#include <hip/hip_bf16.h>
#include <math.h>

#define S_LEN 2048
#define N1 16
#define D 128
#define H 8
#define DI 128
#define K_SEL 512
#define SCALE_F 0.08838834764831845f  /* 1/sqrt(128) */
#define EPS_F 1e-9f
#define STP 136  /* padded LDS row stride (bf16 elems): breaks bank conflicts */

typedef __attribute__((ext_vector_type(8))) __bf16 bf16x8;
typedef __attribute__((ext_vector_type(4))) float f32x4;

static __device__ __forceinline__ ushort f2bf(float x) {
  // round-to-nearest-even fp32 -> bf16 bit pattern
  uint u = __float_as_uint(x);
  uint r = u + 0x7fffu + ((u >> 16) & 1u);
  return (ushort)(r >> 16);
}

// ---------- pre-pass: key/kidx fp32 -> bf16 in workspace ----------
__global__ __launch_bounds__(256)
void prep_bf16(const float* __restrict__ key, const float* __restrict__ kidx,
               ushort* __restrict__ keyb, ushort* __restrict__ kidxb) {
  const int gid = blockIdx.x * 256 + threadIdx.x;  // 0 .. 65535 (S*D/4)
  const float4 kv = ((const float4*)key)[gid];
  ushort4 o;
  o.x = f2bf(kv.x); o.y = f2bf(kv.y); o.z = f2bf(kv.z); o.w = f2bf(kv.w);
  ((ushort4*)keyb)[gid] = o;
  const float4 iv = ((const float4*)kidx)[gid];
  ushort4 p;
  p.x = f2bf(iv.x); p.y = f2bf(iv.y); p.z = f2bf(iv.z); p.w = f2bf(iv.w);
  ((ushort4*)kidxb)[gid] = p;
}

// ---------- main: one block per row t; 4 waves x 128 cols ----------
template <bool PRE>
__global__ __launch_bounds__(256)
void sli_kl_mfma(const float* __restrict__ query,
                 const float* __restrict__ key,
                 const float* __restrict__ qidx,
                 const float* __restrict__ kidx,
                 const float* __restrict__ weights,
                 const int* __restrict__ sidx,
                 const float* __restrict__ smax,
                 const float* __restrict__ ssum,
                 const ushort* __restrict__ keyb,
                 const ushort* __restrict__ kidxb,
                 float* __restrict__ out) {
  const int t = blockIdx.x;
  const int tid = threadIdx.x;
  const int lane = tid & 63;
  const int w = tid >> 6;       // wave id 0..3
  const int lg = lane >> 4;     // lane group 0..3
  const int lr = lane & 15;

  __shared__ ushort aq_l[N1 * STP];
  __shared__ ushort ai_l[N1 * STP];
  __shared__ float a_lds[K_SEL];
  __shared__ float e_lds[K_SEL];
  __shared__ float cn_l[16];
  __shared__ float wg_l[16];
  __shared__ float red[5][4];

  // zero indexer A-tile (rows 8..15 stay zero => scores 0, w=0 => inert)
  for (int i = tid; i < (N1 * STP) / 2; i += 256) ((uint*)ai_l)[i] = 0u;
  if (tid < 16) {
    cn_l[tid] = __expf(-smax[tid * S_LEN + t]) / ssum[tid * S_LEN + t];
  } else if (tid < 32) {
    const int h = tid - 16;
    wg_l[h] = (h < H) ? weights[t * H + h] : 0.f;
  }
  __syncthreads();

  // convert this row's q (16x128) and qi (8x128) into bf16 LDS tiles
  {
    const int row = tid >> 4;            // 0..15
    const int c0 = (tid & 15) * 8;       // 0..120
    const float* src = query + (size_t)t * (N1 * D) + row * D + c0;
    const float4 v0 = *(const float4*)src;
    const float4 v1 = *(const float4*)(src + 4);
    ushort* dst = aq_l + row * STP + c0;
    ushort4 p0, p1;
    p0.x = f2bf(v0.x); p0.y = f2bf(v0.y); p0.z = f2bf(v0.z); p0.w = f2bf(v0.w);
    p1.x = f2bf(v1.x); p1.y = f2bf(v1.y); p1.z = f2bf(v1.z); p1.w = f2bf(v1.w);
    *(ushort4*)dst = p0;
    *(ushort4*)(dst + 4) = p1;
    if (row < H) {
      const float* s2 = qidx + (size_t)t * (H * DI) + row * DI + c0;
      const float4 u0 = *(const float4*)s2;
      const float4 u1 = *(const float4*)(s2 + 4);
      ushort* dsti = ai_l + row * STP + c0;
      ushort4 q0, q1;
      q0.x = f2bf(u0.x); q0.y = f2bf(u0.y); q0.z = f2bf(u0.z); q0.w = f2bf(u0.w);
      q1.x = f2bf(u1.x); q1.y = f2bf(u1.y); q1.z = f2bf(u1.z); q1.w = f2bf(u1.w);
      *(ushort4*)dsti = q0;
      *(ushort4*)(dsti + 4) = q1;
    }
  }
  __syncthreads();

  // A-fragments to registers: row = lane&15, k = ks*32 + lg*8 + (0..7)
  bf16x8 aq[4], ai[4];
#pragma unroll
  for (int ks = 0; ks < 4; ++ks) {
    aq[ks] = *(const bf16x8*)(aq_l + lr * STP + ks * 32 + lg * 8);
    ai[ks] = *(const bf16x8*)(ai_l + lr * STP + ks * 32 + lg * 8);
  }
  float cnl[4], wgl[4];
#pragma unroll
  for (int j = 0; j < 4; ++j) {
    cnl[j] = cn_l[lg * 4 + j];
    wgl[j] = wg_l[lg * 4 + j];
  }

  // preload this lane's 8 column indices (col = w*128 + g*16 + lr)
  int sv[8];
#pragma unroll
  for (int g = 0; g < 8; ++g)
    sv[g] = sidx[t * K_SEL + w * 128 + g * 16 + lr];

#pragma unroll 2
  for (int g = 0; g < 8; ++g) {
    f32x4 cA = {0.f, 0.f, 0.f, 0.f};
    f32x4 cI = {0.f, 0.f, 0.f, 0.f};
    if (PRE) {
      const ushort* kb = keyb + (size_t)sv[g] * D;
      const ushort* kib = kidxb + (size_t)sv[g] * DI;
#pragma unroll
      for (int ks = 0; ks < 4; ++ks) {
        const bf16x8 bA = *(const bf16x8*)(kb + ks * 32 + lg * 8);
        const bf16x8 bI = *(const bf16x8*)(kib + ks * 32 + lg * 8);
        cA = __builtin_amdgcn_mfma_f32_16x16x32_bf16(aq[ks], bA, cA, 0, 0, 0);
        cI = __builtin_amdgcn_mfma_f32_16x16x32_bf16(ai[ks], bI, cI, 0, 0, 0);
      }
    } else {
      const float* kb = key + (size_t)sv[g] * D;
      const float* kib = kidx + (size_t)sv[g] * DI;
#pragma unroll
      for (int ks = 0; ks < 4; ++ks) {
        const float4 a0 = *(const float4*)(kb + ks * 32 + lg * 8);
        const float4 a1 = *(const float4*)(kb + ks * 32 + lg * 8 + 4);
        const float4 b0 = *(const float4*)(kib + ks * 32 + lg * 8);
        const float4 b1 = *(const float4*)(kib + ks * 32 + lg * 8 + 4);
        bf16x8 bA, bI;
        bA[0] = (__bf16)a0.x; bA[1] = (__bf16)a0.y; bA[2] = (__bf16)a0.z; bA[3] = (__bf16)a0.w;
        bA[4] = (__bf16)a1.x; bA[5] = (__bf16)a1.y; bA[6] = (__bf16)a1.z; bA[7] = (__bf16)a1.w;
        bI[0] = (__bf16)b0.x; bI[1] = (__bf16)b0.y; bI[2] = (__bf16)b0.z; bI[3] = (__bf16)b0.w;
        bI[4] = (__bf16)b1.x; bI[5] = (__bf16)b1.y; bI[6] = (__bf16)b1.z; bI[7] = (__bf16)b1.w;
        cA = __builtin_amdgcn_mfma_f32_16x16x32_bf16(aq[ks], bA, cA, 0, 0, 0);
        cI = __builtin_amdgcn_mfma_f32_16x16x32_bf16(ai[ks], bI, cI, 0, 0, 0);
      }
    }
    // C layout: col = lane&15 (this lane's sv[g] col), row(head) = lg*4 + j
    float pa = 0.f, ia = 0.f;
#pragma unroll
    for (int j = 0; j < 4; ++j) {
      pa = fmaf(__expf(cA[j] * SCALE_F), cnl[j], pa);
      ia = fmaf(wgl[j], fmaxf(cI[j], 0.f), ia);
    }
    pa += __shfl_xor(pa, 16); pa += __shfl_xor(pa, 32);
    ia += __shfl_xor(ia, 16); ia += __shfl_xor(ia, 32);
    if (lane < 16) {
      a_lds[w * 128 + g * 16 + lane] = pa;
      e_lds[w * 128 + g * 16 + lane] = ia;
    }
  }
  __syncthreads();

  // ---------- row reductions (unchanged) ----------
  const int wid = w;
  float la = 0.f, le = -INFINITY;
  for (int k = tid; k < K_SEL; k += 256) {
    la += a_lds[k];
    le = fmaxf(le, e_lds[k]);
  }
#pragma unroll
  for (int off = 32; off >= 1; off >>= 1) {
    la += __shfl_xor(la, off);
    le = fmaxf(le, __shfl_xor(le, off));
  }
  if (lane == 0) { red[0][wid] = la; red[1][wid] = le; }
  __syncthreads();
  const float S_a = red[0][0] + red[0][1] + red[0][2] + red[0][3];
  const float M = fmaxf(fmaxf(red[1][0], red[1][1]), fmaxf(red[1][2], red[1][3]));
  const float inv_sa = 1.f / (S_a + EPS_F);

  float z = 0.f, t1 = 0.f, t2 = 0.f;
  for (int k = tid; k < K_SEL; k += 256) {
    const float e = e_lds[k];
    const float pn = a_lds[k] * inv_sa;
    z += __expf(e - M);
    t1 += pn * __logf(pn + EPS_F);
    t2 += pn * e;
  }
#pragma unroll
  for (int off = 32; off >= 1; off >>= 1) {
    z += __shfl_xor(z, off);
    t1 += __shfl_xor(t1, off);
    t2 += __shfl_xor(t2, off);
  }
  if (lane == 0) { red[2][wid] = z; red[3][wid] = t1; red[4][wid] = t2; }
  __syncthreads();

  if (tid == 0) {
    const float Z = red[2][0] + red[2][1] + red[2][2] + red[2][3];
    const float T1 = red[3][0] + red[3][1] + red[3][2] + red[3][3];
    const float T2 = red[4][0] + red[4][1] + red[4][2] + red[4][3];
    const float total_pn = S_a * inv_sa;
    const float kl_row = T1 - T2 + (M + __logf(Z)) * total_pn;
    atomicAdd(out, kl_row * (1.0f / (float)S_LEN));
  }
}

extern "C" void kernel_launch(void* const* d_in, const int* in_sizes, int n_in,
                              void* d_out, int out_size, void* d_ws, size_t ws_size,
                              hipStream_t stream) {
  const float* query = (const float*)d_in[0];
  const float* key = (const float*)d_in[1];
  const float* qidx = (const float*)d_in[2];
  const float* kidx = (const float*)d_in[3];
  const float* weights = (const float*)d_in[4];
  const int* sidx = (const int*)d_in[5];
  const float* smax = (const float*)d_in[6];
  const float* ssum = (const float*)d_in[7];
  float* out = (float*)d_out;

  hipMemsetAsync(out, 0, sizeof(float), stream);

  const size_t need = (size_t)2 * S_LEN * D * sizeof(ushort);  // 1 MiB
  if (ws_size >= need) {
    ushort* keyb = (ushort*)d_ws;
    ushort* kidxb = keyb + (size_t)S_LEN * D;
    prep_bf16<<<dim3((S_LEN * D / 4) / 256), dim3(256), 0, stream>>>(key, kidx, keyb, kidxb);
    sli_kl_mfma<true><<<dim3(S_LEN), dim3(256), 0, stream>>>(
        query, key, qidx, kidx, weights, sidx, smax, ssum, keyb, kidxb, out);
  } else {
    sli_kl_mfma<false><<<dim3(S_LEN), dim3(256), 0, stream>>>(
        query, key, qidx, kidx, weights, sidx, smax, ssum, nullptr, nullptr, out);
  }
}

// Round 4
// 64.891 us; speedup vs baseline: 3.4371x; 1.1440x over previous
//
#include <hip/hip_runtime.h>
#include <hip/hip_bf16.h>
#include <math.h>

#define S_LEN 2048
#define N1 16
#define D 128
#define H 8
#define DI 128
#define K_SEL 512
#define SCALE_F 0.08838834764831845f  /* 1/sqrt(128) */
#define EPS_F 1e-9f

typedef __attribute__((ext_vector_type(8))) __bf16 bf16x8;
typedef __attribute__((ext_vector_type(4))) float f32x4;

static __device__ __forceinline__ ushort f2bf(float x) {
  uint u = __float_as_uint(x);
  uint r = u + 0x7fffu + ((u >> 16) & 1u);
  return (ushort)(r >> 16);
}

static __device__ __forceinline__ bf16x8 cvt8(float4 v0, float4 v1) {
  bf16x8 a;
  a[0] = (__bf16)v0.x; a[1] = (__bf16)v0.y; a[2] = (__bf16)v0.z; a[3] = (__bf16)v0.w;
  a[4] = (__bf16)v1.x; a[5] = (__bf16)v1.y; a[6] = (__bf16)v1.z; a[7] = (__bf16)v1.w;
  return a;
}

// ---------- pre-pass: key/kidx fp32 -> bf16 in workspace ----------
__global__ __launch_bounds__(256)
void prep_bf16(const float* __restrict__ key, const float* __restrict__ kidx,
               ushort* __restrict__ keyb, ushort* __restrict__ kidxb) {
  const int gid = blockIdx.x * 256 + threadIdx.x;  // 0 .. 65535 (S*D/4)
  const float4 kv = ((const float4*)key)[gid];
  ushort4 o;
  o.x = f2bf(kv.x); o.y = f2bf(kv.y); o.z = f2bf(kv.z); o.w = f2bf(kv.w);
  ((ushort4*)keyb)[gid] = o;
  const float4 iv = ((const float4*)kidx)[gid];
  ushort4 p;
  p.x = f2bf(iv.x); p.y = f2bf(iv.y); p.z = f2bf(iv.z); p.w = f2bf(iv.w);
  ((ushort4*)kidxb)[gid] = p;
}

// ---------- main: one block per row t; 4 waves x 128 cols; no LDS tiles ----
__global__ __launch_bounds__(256)
void sli_kl_mfma(const float* __restrict__ query,
                 const float* __restrict__ qidx,
                 const float* __restrict__ weights,
                 const int* __restrict__ sidx,
                 const float* __restrict__ smax,
                 const float* __restrict__ ssum,
                 const ushort* __restrict__ keyb,
                 const ushort* __restrict__ kidxb,
                 float* __restrict__ out) {
  const int t = blockIdx.x;
  const int tid = threadIdx.x;
  const int lane = tid & 63;
  const int w = tid >> 6;       // wave id 0..3
  const int lg = lane >> 4;     // lane group 0..3 -> k-slice / C-row group
  const int lr = lane & 15;     // A-row (head) / B-col within group

  __shared__ float red[5][4];

  // ---- per-lane column indices for this wave's 128 columns ----
  int sv[8];
#pragma unroll
  for (int g = 0; g < 8; ++g)
    sv[g] = sidx[t * K_SEL + w * 128 + g * 16 + lr];

  // ---- A fragments straight from global, fp32 -> bf16 in-register ----
  // A layout (16x16x32): row = lane&15, k = (lane>>4)*8 + j, ks*32 k-step.
  bf16x8 aq[4], ai[4];
  {
    const float* qb = query + (size_t)t * (N1 * D) + lr * D;
#pragma unroll
    for (int ks = 0; ks < 4; ++ks) {
      const int off = ks * 32 + lg * 8;
      aq[ks] = cvt8(*(const float4*)(qb + off), *(const float4*)(qb + off + 4));
    }
    if (lr < H) {
      const float* ib = qidx + (size_t)t * (H * DI) + lr * DI;
#pragma unroll
      for (int ks = 0; ks < 4; ++ks) {
        const int off = ks * 32 + lg * 8;
        ai[ks] = cvt8(*(const float4*)(ib + off), *(const float4*)(ib + off + 4));
      }
    } else {
#pragma unroll
      for (int ks = 0; ks < 4; ++ks) {
        bf16x8 zz = {};
        ai[ks] = zz;
      }
    }
  }

  // ---- per-lane row constants for this lane's 4 C-rows (heads lg*4+j) ----
  float cnl[4], wgl[4];
#pragma unroll
  for (int j = 0; j < 4; ++j) {
    const int head = lg * 4 + j;
    cnl[j] = __expf(-smax[head * S_LEN + t]) / ssum[head * S_LEN + t];
    wgl[j] = (head < H) ? weights[t * H + head] : 0.f;
  }

  // ---- software-pipelined main loop: distance-1 prefetch, static bufs ----
  bf16x8 bA[2][4], bI[2][4];
#pragma unroll
  for (int ks = 0; ks < 4; ++ks) {
    bA[0][ks] = *(const bf16x8*)(keyb + (size_t)sv[0] * D + ks * 32 + lg * 8);
    bI[0][ks] = *(const bf16x8*)(kidxb + (size_t)sv[0] * DI + ks * 32 + lg * 8);
  }

  float pa[8], ia[8];
#pragma unroll
  for (int g = 0; g < 8; ++g) {
    const int cur = g & 1;
    const int nxt = cur ^ 1;
    if (g < 7) {
#pragma unroll
      for (int ks = 0; ks < 4; ++ks) {
        bA[nxt][ks] = *(const bf16x8*)(keyb + (size_t)sv[g + 1] * D + ks * 32 + lg * 8);
        bI[nxt][ks] = *(const bf16x8*)(kidxb + (size_t)sv[g + 1] * DI + ks * 32 + lg * 8);
      }
    }
    f32x4 cA = {0.f, 0.f, 0.f, 0.f};
    f32x4 cI = {0.f, 0.f, 0.f, 0.f};
#pragma unroll
    for (int ks = 0; ks < 4; ++ks) {
      cA = __builtin_amdgcn_mfma_f32_16x16x32_bf16(aq[ks], bA[cur][ks], cA, 0, 0, 0);
      cI = __builtin_amdgcn_mfma_f32_16x16x32_bf16(ai[ks], bI[cur][ks], cI, 0, 0, 0);
    }
    // C layout: col = lane&15 (this lane's sv[g] col), row(head) = lg*4+j
    float p = 0.f, e = 0.f;
#pragma unroll
    for (int j = 0; j < 4; ++j) {
      p = fmaf(__expf(cA[j] * SCALE_F), cnl[j], p);
      e = fmaf(wgl[j], fmaxf(cI[j], 0.f), e);
    }
    pa[g] = p;
    ia[g] = e;
  }

  // ---- cross-lane-group combine (sum over 16 heads), out of main loop ----
#pragma unroll
  for (int g = 0; g < 8; ++g) {
    pa[g] += __shfl_xor(pa[g], 16); pa[g] += __shfl_xor(pa[g], 32);
    ia[g] += __shfl_xor(ia[g], 16); ia[g] += __shfl_xor(ia[g], 32);
  }

  // ---- pass 1: S_a = sum pa, M = max ia (reduce within 16-lane group) ----
  float la = 0.f, le = -INFINITY;
#pragma unroll
  for (int g = 0; g < 8; ++g) {
    la += pa[g];
    le = fmaxf(le, ia[g]);
  }
#pragma unroll
  for (int off = 8; off >= 1; off >>= 1) {
    la += __shfl_xor(la, off);
    le = fmaxf(le, __shfl_xor(le, off));
  }
  if (lane == 0) { red[0][w] = la; red[1][w] = le; }
  __syncthreads();
  const float S_a = red[0][0] + red[0][1] + red[0][2] + red[0][3];
  const float M = fmaxf(fmaxf(red[1][0], red[1][1]), fmaxf(red[1][2], red[1][3]));
  const float inv_sa = 1.f / (S_a + EPS_F);

  // ---- pass 2: Z, T1, T2 from registers ----
  float z = 0.f, t1 = 0.f, t2 = 0.f;
#pragma unroll
  for (int g = 0; g < 8; ++g) {
    const float e = ia[g];
    const float pn = pa[g] * inv_sa;
    z += __expf(e - M);
    t1 += pn * __logf(pn + EPS_F);
    t2 += pn * e;
  }
#pragma unroll
  for (int off = 8; off >= 1; off >>= 1) {
    z += __shfl_xor(z, off);
    t1 += __shfl_xor(t1, off);
    t2 += __shfl_xor(t2, off);
  }
  if (lane == 0) { red[2][w] = z; red[3][w] = t1; red[4][w] = t2; }
  __syncthreads();

  if (tid == 0) {
    const float Z = red[2][0] + red[2][1] + red[2][2] + red[2][3];
    const float T1 = red[3][0] + red[3][1] + red[3][2] + red[3][3];
    const float T2 = red[4][0] + red[4][1] + red[4][2] + red[4][3];
    const float total_pn = S_a * inv_sa;
    const float kl_row = T1 - T2 + (M + __logf(Z)) * total_pn;
    atomicAdd(out, kl_row * (1.0f / (float)S_LEN));
  }
}

extern "C" void kernel_launch(void* const* d_in, const int* in_sizes, int n_in,
                              void* d_out, int out_size, void* d_ws, size_t ws_size,
                              hipStream_t stream) {
  const float* query = (const float*)d_in[0];
  const float* key = (const float*)d_in[1];
  const float* qidx = (const float*)d_in[2];
  const float* kidx = (const float*)d_in[3];
  const float* weights = (const float*)d_in[4];
  const int* sidx = (const int*)d_in[5];
  const float* smax = (const float*)d_in[6];
  const float* ssum = (const float*)d_in[7];
  float* out = (float*)d_out;

  hipMemsetAsync(out, 0, sizeof(float), stream);

  ushort* keyb = (ushort*)d_ws;
  ushort* kidxb = keyb + (size_t)S_LEN * D;
  prep_bf16<<<dim3((S_LEN * D / 4) / 256), dim3(256), 0, stream>>>(key, kidx, keyb, kidxb);
  sli_kl_mfma<<<dim3(S_LEN), dim3(256), 0, stream>>>(
      query, qidx, weights, sidx, smax, ssum, keyb, kidxb, out);
}